// Round 5
// baseline (189.595 us; speedup 1.0000x reference)
//
#include <hip/hip_runtime.h>
#include <hip/hip_bf16.h>

#define NB 16
#define NN 1024
#define FOUT 64
#define NH 4
#define LRELU_A 0.2f
#define CAP 192   // max edges/row; density 5% -> mean 51.2, sd ~7

typedef __attribute__((ext_vector_type(8))) short bf16x8;
typedef __attribute__((ext_vector_type(4))) float f32x4;

#define WFENCE() asm volatile("s_waitcnt lgkmcnt(0)" ::: "memory")

__device__ __forceinline__ float lrelu(float s) { return fmaxf(s, LRELU_A * s); }

__device__ __forceinline__ float4 min4(float4 a, float4 b) {
    return make_float4(fminf(a.x,b.x), fminf(a.y,b.y), fminf(a.z,b.z), fminf(a.w,b.w));
}
__device__ __forceinline__ float4 max4(float4 a, float4 b) {
    return make_float4(fmaxf(a.x,b.x), fmaxf(a.y,b.y), fmaxf(a.z,b.z), fmaxf(a.w,b.w));
}

__device__ __forceinline__ unsigned int pk2(float a, float b) {
    union { __hip_bfloat16 h; unsigned short u; } ua, ub;
    ua.h = __float2bfloat16(a); ub.h = __float2bfloat16(b);
    return (unsigned int)ua.u | ((unsigned int)ub.u << 16);
}
__device__ __forceinline__ unsigned short bfbits(float a) {
    union { __hip_bfloat16 h; unsigned short u; } ua;
    ua.h = __float2bfloat16(a);
    return ua.u;
}
// swizzled 16B-chunk offset within a [rows][16 chunks] tile (T2-style: c ^= row&7)
__device__ __forceinline__ int toff(int r, int c) { return (r * 16 + (c ^ (r & 7))) * 16; }

// ---------------------------------------------------------------------------
// k_prep: WbT_swz[col][k] bf16, pre-transposed + pre-swizzled so k_proj's LDS
// stage is a linear copy. col = head*64+o, chunk c holds k=8c..8c+7.
// ---------------------------------------------------------------------------
__global__ __launch_bounds__(256) void k_prep(const float* __restrict__ W,
                                              uint4* __restrict__ WbT)
{
    int gid  = blockIdx.x * 256 + threadIdx.x;   // 0..4095 = 256 cols x 16 chunks
    int col  = gid >> 4, c = gid & 15;
    int head = col >> 6, o = col & 63;
    const float* wp = W + head * 8192 + (c * 8) * 64 + o;
    float v[8];
    #pragma unroll
    for (int j = 0; j < 8; ++j) v[j] = wp[j * 64];
    uint4 outv = { pk2(v[0], v[1]), pk2(v[2], v[3]), pk2(v[4], v[5]), pk2(v[6], v[7]) };
    WbT[col * 16 + (c ^ (col & 7))] = outv;
}

// ---------------------------------------------------------------------------
// k_proj (MFMA bf16): h[b,head,n,o] = concat(x,SE).W, stored bf16.
// Tile 128 rows x 64 cols (one head per col-quarter). 4 waves x 32 rows.
// A,B in XOR-swizzled LDS; C bounced via LDS for coalesced uint4 stores.
// ---------------------------------------------------------------------------
__global__ __launch_bounds__(256) void k_proj(const float* __restrict__ x,
                                              const float* __restrict__ SE,
                                              const uint4* __restrict__ WbT,
                                              unsigned int* __restrict__ hbu)
{
    __shared__ char smem[49152];          // A 32KB + B 16KB
    char* Ab = smem;
    char* Bb = smem + 32768;
    const int tid = threadIdx.x;
    const int rt  = blockIdx.x >> 2;      // row-tile (128 rows)
    const int ch  = blockIdx.x & 3;       // col-quarter == head

    // --- A stage: 128 rows x 128 k (bf16, swizzled) ---
    {
        const int row = tid & 127, kh = tid >> 7;
        const int rg = rt * 128 + row;
        const int bb = rg >> 10, nn = rg & 1023;
        const float4* src = (kh == 0) ? (const float4*)(x + ((size_t)(bb * NN + nn)) * 64)
                                      : (const float4*)(SE + (size_t)nn * 64);
        #pragma unroll
        for (int q = 0; q < 8; ++q) {
            float4 u0 = src[q * 2], u1 = src[q * 2 + 1];
            uint4 pkv = { pk2(u0.x, u0.y), pk2(u0.z, u0.w), pk2(u1.x, u1.y), pk2(u1.z, u1.w) };
            *(uint4*)(Ab + toff(row, kh * 8 + q)) = pkv;
        }
    }
    // --- B stage: linear 16KB copy of this quarter's pre-swizzled WbT ---
    {
        const uint4* wsrc = WbT + ch * 1024;
        #pragma unroll
        for (int q = 0; q < 4; ++q) ((uint4*)Bb)[tid + 256 * q] = wsrc[tid + 256 * q];
    }
    __syncthreads();

    // --- MFMA: wave w = rows 32w..32w+31, all 64 cols ---
    const int l = tid & 63, w = tid >> 6;
    const int r0 = 32 * w + (l & 15);
    const int ci = l >> 4;
    f32x4 acc[2][4];
    #pragma unroll
    for (int a = 0; a < 2; ++a)
        #pragma unroll
        for (int bf = 0; bf < 4; ++bf) { acc[a][bf][0]=0.f; acc[a][bf][1]=0.f; acc[a][bf][2]=0.f; acc[a][bf][3]=0.f; }

    #pragma unroll
    for (int ks = 0; ks < 4; ++ks) {
        const int c = 4 * ks + ci;
        bf16x8 A0 = *(const bf16x8*)(Ab + toff(r0,      c));
        bf16x8 A1 = *(const bf16x8*)(Ab + toff(r0 + 16, c));
        #pragma unroll
        for (int bf = 0; bf < 4; ++bf) {
            bf16x8 Bf = *(const bf16x8*)(Bb + toff(16 * bf + (l & 15), c));
            acc[0][bf] = __builtin_amdgcn_mfma_f32_16x16x32_bf16(A0, Bf, acc[0][bf], 0, 0, 0);
            acc[1][bf] = __builtin_amdgcn_mfma_f32_16x16x32_bf16(A1, Bf, acc[1][bf], 0, 0, 0);
        }
    }
    __syncthreads();   // A region reused as C staging below

    // --- epilogue: C -> LDS (bf16) -> coalesced global ---
    unsigned short* cst = (unsigned short*)smem + w * 2048;   // 32 rows x 64 cols
    #pragma unroll
    for (int a = 0; a < 2; ++a)
        #pragma unroll
        for (int bf = 0; bf < 4; ++bf)
            #pragma unroll
            for (int reg = 0; reg < 4; ++reg) {
                int r   = 16 * a + (l >> 4) * 4 + reg;      // C/D: col=lane&15, row=(lane>>4)*4+reg
                int col = 16 * bf + (l & 15);
                cst[r * 64 + col] = bfbits(acc[a][bf][reg]);
            }
    WFENCE();
    const uint4* csv = (const uint4*)cst;                    // 256 uint4
    #pragma unroll
    for (int p = 0; p < 4; ++p) {
        int idx = p * 64 + l;
        uint4 v = csv[idx];
        int r = idx >> 3, o8 = idx & 7;
        int ng = rt * 128 + 32 * w + r;
        int bb = ng >> 10, n2 = ng & 1023;
        ((uint4*)hbu)[((size_t)(bb * NH + ch) * NN + n2) * 8 + o8] = v;
    }
}

// ---------------------------------------------------------------------------
// k_f12: f1[b,n,h]=h.a1, f2 likewise, from bf16 h. One wave per (b,n).
// ---------------------------------------------------------------------------
__global__ __launch_bounds__(256) void k_f12(const unsigned short* __restrict__ hb,
                                             const float* __restrict__ a1,
                                             const float* __restrict__ a2,
                                             float* __restrict__ f1p,
                                             float* __restrict__ f2p)
{
    int task = blockIdx.x * 4 + (threadIdx.x >> 6);
    int lane = threadIdx.x & 63;
    int b = task >> 10, n = task & 1023;
    #pragma unroll
    for (int hh = 0; hh < NH; ++hh) {
        unsigned short us = hb[((size_t)(b * NH + hh) * NN + n) * 64 + lane];
        float v  = __uint_as_float((unsigned int)us << 16);
        float s1 = v * a1[hh * 64 + lane];
        float s2 = v * a2[hh * 64 + lane];
        #pragma unroll
        for (int m = 32; m > 0; m >>= 1) { s1 += __shfl_xor(s1, m); s2 += __shfl_xor(s2, m); }
        if (lane == 0) {
            f1p[(b * NN + n) * 4 + hh] = s1;
            f2p[(b * NN + n) * 4 + hh] = s2;
        }
    }
}

// ---------------------------------------------------------------------------
// k_stats: per-(b,g,j) softmax-over-i stats. Wave-parallel min/max (no tree).
// ---------------------------------------------------------------------------
__global__ __launch_bounds__(256) void k_stats(const float* __restrict__ f1p,
                                               const float* __restrict__ f2p,
                                               const float* __restrict__ P_l,
                                               float* __restrict__ Mp,
                                               float* __restrict__ Rp)
{
    __shared__ float4 f1s[1024];
    __shared__ float4 red[8][32];
    const int tid  = threadIdx.x;
    const int lane = tid & 63;
    const int b   = blockIdx.x >> 5;
    const int jt  = blockIdx.x & 31;
    const float4* f1p4 = (const float4*)f1p;
    const float4* f2p4 = (const float4*)f2p;

    #pragma unroll
    for (int q = 0; q < 4; ++q) f1s[tid + 256 * q] = f1p4[b * NN + tid + 256 * q];
    __syncthreads();

    // per-wave butterfly min/max over all 1024 entries
    float4 mn = make_float4( INFINITY,  INFINITY,  INFINITY,  INFINITY);
    float4 mx = make_float4(-INFINITY, -INFINITY, -INFINITY, -INFINITY);
    #pragma unroll
    for (int q = 0; q < 16; ++q) {
        float4 v = f1s[lane + 64 * q];
        mn = min4(mn, v);
        mx = max4(mx, v);
    }
    #pragma unroll
    for (int m = 32; m > 0; m >>= 1) {
        float4 on = make_float4(__shfl_xor(mn.x, m), __shfl_xor(mn.y, m), __shfl_xor(mn.z, m), __shfl_xor(mn.w, m));
        float4 ox = make_float4(__shfl_xor(mx.x, m), __shfl_xor(mx.y, m), __shfl_xor(mx.z, m), __shfl_xor(mx.w, m));
        mn = min4(mn, on);
        mx = max4(mx, ox);
    }

    float pl[4][4];
    #pragma unroll
    for (int hh = 0; hh < 4; ++hh)
        #pragma unroll
        for (int g = 0; g < 4; ++g) pl[hh][g] = P_l[hh * 4 + g];

    const int jj = tid & 31, ic = tid >> 5;
    const int j  = jt * 32 + jj;
    float4 f2v = f2p4[b * NN + j];
    float f2a[4] = {f2v.x, f2v.y, f2v.z, f2v.w};
    float mna[4] = {mn.x, mn.y, mn.z, mn.w};
    float mxa[4] = {mx.x, mx.y, mx.z, mx.w};
    float mub[4];
    #pragma unroll
    for (int g = 0; g < 4; ++g) {
        float s = 0.f;
        #pragma unroll
        for (int hh = 0; hh < 4; ++hh) {
            float base = (pl[hh][g] >= 0.f ? mxa[hh] : mna[hh]) + f2a[hh];
            s = fmaf(pl[hh][g], lrelu(base), s);
        }
        mub[g] = s;
    }

    float d[4] = {0.f, 0.f, 0.f, 0.f};
    const int i0 = ic * 128;
    #pragma unroll 2
    for (int i = i0; i < i0 + 128; ++i) {
        float4 f1v = f1s[i];
        float l0 = lrelu(f1v.x + f2a[0]);
        float l1 = lrelu(f1v.y + f2a[1]);
        float l2 = lrelu(f1v.z + f2a[2]);
        float l3 = lrelu(f1v.w + f2a[3]);
        #pragma unroll
        for (int g = 0; g < 4; ++g) {
            float e = fmaf(pl[0][g], l0, fmaf(pl[1][g], l1, fmaf(pl[2][g], l2, pl[3][g] * l3)));
            d[g] += __expf(e - mub[g]);
        }
    }
    red[ic][jj] = make_float4(d[0], d[1], d[2], d[3]);
    __syncthreads();
    if (ic == 0) {
        float4 t = red[0][jj];
        #pragma unroll
        for (int r = 1; r < 8; ++r) {
            float4 u = red[r][jj];
            t.x += u.x; t.y += u.y; t.z += u.z; t.w += u.w;
        }
        ((float4*)Rp)[b * NN + j] = make_float4(1.f / t.x, 1.f / t.y, 1.f / t.z, 1.f / t.w);
        ((float4*)Mp)[b * NN + j] = make_float4(mub[0], mub[1], mub[2], mub[3]);
    }
}

// ---------------------------------------------------------------------------
// k_agg: wave-per-row, barrier-free (wave-local LDS fences), 8-deep gather.
// ---------------------------------------------------------------------------
__global__ __launch_bounds__(256) void k_agg(const float* __restrict__ adj,
                                             const float* __restrict__ x,
                                             const unsigned int* __restrict__ hb,
                                             const float* __restrict__ f1p,
                                             const float* __restrict__ f2p,
                                             const float* __restrict__ Mp,
                                             const float* __restrict__ Rp,
                                             const float* __restrict__ P_l,
                                             const float* __restrict__ P_w,
                                             float* __restrict__ out)
{
    __shared__ int   jl[4][CAP + 8];
    __shared__ float attlT[4][4][CAP + 8];   // [wave][head][edge]
    const int tid  = threadIdx.x;
    const int w    = tid >> 6;
    const int lane = tid & 63;
    const int row  = blockIdx.x * 4 + w;    // b*NN + i
    const int b    = row >> 10;

    // --- adj row load ---
    const float4* arow = (const float4*)adj + (size_t)row * 256;
    float4 av[4];
    #pragma unroll
    for (int q = 0; q < 4; ++q) av[q] = arow[lane + 64 * q];

    // --- in-wave ballot compaction ---
    const unsigned long long lt = (1ull << lane) - 1ull;
    int cnt = 0;
    #pragma unroll
    for (int q = 0; q < 4; ++q) {
        float vv[4] = {av[q].x, av[q].y, av[q].z, av[q].w};
        #pragma unroll
        for (int c = 0; c < 4; ++c) {
            bool nz = (vv[c] != 0.f);
            unsigned long long mask = __ballot(nz);
            if (nz) {
                int pos = cnt + __popcll(mask & lt);
                if (pos < CAP) jl[w][pos] = (lane + 64 * q) * 4 + c;
            }
            cnt += __popcll(mask);
        }
    }
    if (cnt > CAP) cnt = CAP;
    WFENCE();

    // --- att recompute (lane kk -> edge kk) + zero-pad 8 slots ---
    float pl[4][4], pw[4][4];
    #pragma unroll
    for (int a_ = 0; a_ < 4; ++a_)
        #pragma unroll
        for (int g = 0; g < 4; ++g) {
            pl[a_][g] = P_l[a_ * 4 + g];
            pw[a_][g] = P_w[a_ * 4 + g];
        }
    const float4 f1v = ((const float4*)f1p)[row];
    for (int base = 0; base < cnt; base += 64) {
        int kk = base + lane;
        if (kk < cnt) {
            int j = jl[w][kk];
            float4 f2v = ((const float4*)f2p)[b * NN + j];
            float4 mv  = ((const float4*)Mp)[b * NN + j];
            float4 rv  = ((const float4*)Rp)[b * NN + j];
            float l0 = lrelu(f1v.x + f2v.x);
            float l1 = lrelu(f1v.y + f2v.y);
            float l2 = lrelu(f1v.z + f2v.z);
            float l3 = lrelu(f1v.w + f2v.w);
            float p0 = __expf(fmaf(pl[0][0], l0, fmaf(pl[1][0], l1, fmaf(pl[2][0], l2, pl[3][0] * l3))) - mv.x) * rv.x;
            float p1 = __expf(fmaf(pl[0][1], l0, fmaf(pl[1][1], l1, fmaf(pl[2][1], l2, pl[3][1] * l3))) - mv.y) * rv.y;
            float p2 = __expf(fmaf(pl[0][2], l0, fmaf(pl[1][2], l1, fmaf(pl[2][2], l2, pl[3][2] * l3))) - mv.z) * rv.z;
            float p3 = __expf(fmaf(pl[0][3], l0, fmaf(pl[1][3], l1, fmaf(pl[2][3], l2, pl[3][3] * l3))) - mv.w) * rv.w;
            #pragma unroll
            for (int g = 0; g < 4; ++g)
                attlT[w][g][kk] =
                    fmaf(p0, pw[0][g], fmaf(p1, pw[1][g], fmaf(p2, pw[2][g], p3 * pw[3][g])));
        }
    }
    if (lane < 8) {
        jl[w][cnt + lane] = 0;
        #pragma unroll
        for (int g = 0; g < 4; ++g) attlT[w][g][cnt + lane] = 0.f;
    }
    WFENCE();

    // --- gather: lane = (hh, o-quad), 8 edges/iter with 8 loads in flight ---
    const int hh = lane >> 4;
    const int og = lane & 15;
    const uint2* hrow = (const uint2*)hb + ((size_t)(b * NH + hh) * NN) * 16 + og;
    const float* atp = &attlT[w][hh][0];
    float a0 = 0.f, a1_ = 0.f, a2_ = 0.f, a3_ = 0.f;
    #pragma unroll 1
    for (int base = 0; base < cnt; base += 8) {
        const int4   ja = *(const int4*)&jl[w][base];
        const int4   jb = *(const int4*)&jl[w][base + 4];
        const float4 ta = *(const float4*)&atp[base];
        const float4 tb = *(const float4*)&atp[base + 4];
        uint2 u0 = hrow[(size_t)ja.x * 16];
        uint2 u1 = hrow[(size_t)ja.y * 16];
        uint2 u2 = hrow[(size_t)ja.z * 16];
        uint2 u3 = hrow[(size_t)ja.w * 16];
        uint2 u4 = hrow[(size_t)jb.x * 16];
        uint2 u5 = hrow[(size_t)jb.y * 16];
        uint2 u6 = hrow[(size_t)jb.z * 16];
        uint2 u7 = hrow[(size_t)jb.w * 16];
        a0 = fmaf(ta.x, __uint_as_float(u0.x << 16), a0);
        a1_ = fmaf(ta.x, __uint_as_float(u0.x & 0xffff0000u), a1_);
        a2_ = fmaf(ta.x, __uint_as_float(u0.y << 16), a2_);
        a3_ = fmaf(ta.x, __uint_as_float(u0.y & 0xffff0000u), a3_);
        a0 = fmaf(ta.y, __uint_as_float(u1.x << 16), a0);
        a1_ = fmaf(ta.y, __uint_as_float(u1.x & 0xffff0000u), a1_);
        a2_ = fmaf(ta.y, __uint_as_float(u1.y << 16), a2_);
        a3_ = fmaf(ta.y, __uint_as_float(u1.y & 0xffff0000u), a3_);
        a0 = fmaf(ta.z, __uint_as_float(u2.x << 16), a0);
        a1_ = fmaf(ta.z, __uint_as_float(u2.x & 0xffff0000u), a1_);
        a2_ = fmaf(ta.z, __uint_as_float(u2.y << 16), a2_);
        a3_ = fmaf(ta.z, __uint_as_float(u2.y & 0xffff0000u), a3_);
        a0 = fmaf(ta.w, __uint_as_float(u3.x << 16), a0);
        a1_ = fmaf(ta.w, __uint_as_float(u3.x & 0xffff0000u), a1_);
        a2_ = fmaf(ta.w, __uint_as_float(u3.y << 16), a2_);
        a3_ = fmaf(ta.w, __uint_as_float(u3.y & 0xffff0000u), a3_);
        a0 = fmaf(tb.x, __uint_as_float(u4.x << 16), a0);
        a1_ = fmaf(tb.x, __uint_as_float(u4.x & 0xffff0000u), a1_);
        a2_ = fmaf(tb.x, __uint_as_float(u4.y << 16), a2_);
        a3_ = fmaf(tb.x, __uint_as_float(u4.y & 0xffff0000u), a3_);
        a0 = fmaf(tb.y, __uint_as_float(u5.x << 16), a0);
        a1_ = fmaf(tb.y, __uint_as_float(u5.x & 0xffff0000u), a1_);
        a2_ = fmaf(tb.y, __uint_as_float(u5.y << 16), a2_);
        a3_ = fmaf(tb.y, __uint_as_float(u5.y & 0xffff0000u), a3_);
        a0 = fmaf(tb.z, __uint_as_float(u6.x << 16), a0);
        a1_ = fmaf(tb.z, __uint_as_float(u6.x & 0xffff0000u), a1_);
        a2_ = fmaf(tb.z, __uint_as_float(u6.y << 16), a2_);
        a3_ = fmaf(tb.z, __uint_as_float(u6.y & 0xffff0000u), a3_);
        a0 = fmaf(tb.w, __uint_as_float(u7.x << 16), a0);
        a1_ = fmaf(tb.w, __uint_as_float(u7.x & 0xffff0000u), a1_);
        a2_ = fmaf(tb.w, __uint_as_float(u7.y << 16), a2_);
        a3_ = fmaf(tb.w, __uint_as_float(u7.y & 0xffff0000u), a3_);
    }
    float4 xr = ((const float4*)x)[row * 16 + og];
    float r0 = a0  + xr.x;
    float r1 = a1_ + xr.y;
    float r2 = a2_ + xr.z;
    float r3 = a3_ + xr.w;
    float4 o4;
    o4.x = (r0 > 0.f) ? r0 : (__expf(r0) - 1.f);
    o4.y = (r1 > 0.f) ? r1 : (__expf(r1) - 1.f);
    o4.z = (r2 > 0.f) ? r2 : (__expf(r2) - 1.f);
    o4.w = (r3 > 0.f) ? r3 : (__expf(r3) - 1.f);
    ((float4*)out)[(size_t)row * 64 + hh * 16 + og] = o4;
}

// ---------------------------------------------------------------------------
extern "C" void kernel_launch(void* const* d_in, const int* in_sizes, int n_in,
                              void* d_out, int out_size, void* d_ws, size_t ws_size,
                              hipStream_t stream)
{
    (void)in_sizes; (void)n_in; (void)out_size; (void)ws_size;
    const float* x   = (const float*)d_in[0];
    const float* adj = (const float*)d_in[1];
    const float* SE  = (const float*)d_in[2];
    const float* W   = (const float*)d_in[3];
    const float* a1  = (const float*)d_in[4];
    const float* a2  = (const float*)d_in[5];
    const float* P_l = (const float*)d_in[6];
    const float* P_w = (const float*)d_in[7];
    float* out = (float*)d_out;

    float* f1p = (float*)d_ws;                       // 65536 floats
    float* f2p = f1p + 65536;
    float* Mp  = f2p + 65536;
    float* Rp  = Mp  + 65536;
    unsigned int* hbu = (unsigned int*)(Rp + 65536); // 2M uints = 8 MB (bf16 h)
    uint4* WbT = (uint4*)(hbu + 2097152);            // 64 KB pre-swizzled bf16 W^T

    k_prep <<<16,   256, 0, stream>>>(W, WbT);
    k_proj <<<512,  256, 0, stream>>>(x, SE, WbT, hbu);
    k_f12  <<<4096, 256, 0, stream>>>((const unsigned short*)hbu, a1, a2, f1p, f2p);
    k_stats<<<512,  256, 0, stream>>>(f1p, f2p, P_l, Mp, Rp);
    k_agg  <<<4096, 256, 0, stream>>>(adj, x, hbu, f1p, f2p, Mp, Rp, P_l, P_w, out);
}

// Round 6
// 171.869 us; speedup vs baseline: 1.1031x; 1.1031x over previous
//
#include <hip/hip_runtime.h>
#include <hip/hip_bf16.h>

#define NB 16
#define NN 1024
#define FOUT 64
#define NH 4
#define LRELU_A 0.2f
#define CAP 192   // max edges/row; density 5% -> mean 51.2, sd ~7

typedef __attribute__((ext_vector_type(8))) short bf16x8;
typedef __attribute__((ext_vector_type(4))) float f32x4;

#define WFENCE() asm volatile("s_waitcnt lgkmcnt(0)" ::: "memory")

__device__ __forceinline__ float lrelu(float s) { return fmaxf(s, LRELU_A * s); }

__device__ __forceinline__ float4 min4(float4 a, float4 b) {
    return make_float4(fminf(a.x,b.x), fminf(a.y,b.y), fminf(a.z,b.z), fminf(a.w,b.w));
}
__device__ __forceinline__ float4 max4(float4 a, float4 b) {
    return make_float4(fmaxf(a.x,b.x), fmaxf(a.y,b.y), fmaxf(a.z,b.z), fmaxf(a.w,b.w));
}

__device__ __forceinline__ unsigned int pk2(float a, float b) {
    union { __hip_bfloat16 h; unsigned short u; } ua, ub;
    ua.h = __float2bfloat16(a); ub.h = __float2bfloat16(b);
    return (unsigned int)ua.u | ((unsigned int)ub.u << 16);
}
__device__ __forceinline__ unsigned short bfbits(float a) {
    union { __hip_bfloat16 h; unsigned short u; } ua;
    ua.h = __float2bfloat16(a);
    return ua.u;
}
// swizzled 16B-chunk offset within a [rows][16 chunks] tile (T2-style: c ^= row&7)
__device__ __forceinline__ int toff(int r, int c) { return (r * 16 + (c ^ (r & 7))) * 16; }

// ---------------------------------------------------------------------------
// k_proj (MFMA bf16): h[b,head,n,o] = concat(x,SE).W -> bf16; ALSO
// f1[b,n,h]=h.a1, f2[b,n,h]=h.a2 computed EXACTLY from the f32 accumulators.
// Tile 128 rows x 64 cols (one head per block). W transform done inline.
// ---------------------------------------------------------------------------
__global__ __launch_bounds__(256) void k_proj(const float* __restrict__ x,
                                              const float* __restrict__ SE,
                                              const float* __restrict__ W,
                                              const float* __restrict__ a1,
                                              const float* __restrict__ a2,
                                              unsigned int* __restrict__ hbu,
                                              float* __restrict__ f1p,
                                              float* __restrict__ f2p)
{
    __shared__ char smem[49152];          // A 32KB + B 16KB
    char* Ab = smem;
    char* Bb = smem + 32768;
    const int tid = threadIdx.x;
    const int rt  = blockIdx.x >> 2;      // row-tile (128 rows)
    const int ch  = blockIdx.x & 3;       // head

    // --- A stage: 128 rows x 128 k (bf16, swizzled) ---
    {
        const int row = tid & 127, kh = tid >> 7;
        const int rg = rt * 128 + row;
        const int bb = rg >> 10, nn = rg & 1023;
        const float4* src = (kh == 0) ? (const float4*)(x + ((size_t)(bb * NN + nn)) * 64)
                                      : (const float4*)(SE + (size_t)nn * 64);
        #pragma unroll
        for (int q = 0; q < 8; ++q) {
            float4 u0 = src[q * 2], u1 = src[q * 2 + 1];
            uint4 pkv = { pk2(u0.x, u0.y), pk2(u0.z, u0.w), pk2(u1.x, u1.y), pk2(u1.z, u1.w) };
            *(uint4*)(Ab + toff(row, kh * 8 + q)) = pkv;
        }
    }
    // --- B stage: inline transform of this head's W quarter (f32 -> bf16 swz) ---
    {
        const float* wbase = W + ch * 8192;
        #pragma unroll
        for (int q = 0; q < 4; ++q) {
            int gid = tid + 256 * q;      // 0..1023: col = gid&63, chunk c = gid>>6
            int col = gid & 63, c = gid >> 6;
            const float* wp = wbase + (c * 8) * 64 + col;
            float v[8];
            #pragma unroll
            for (int j = 0; j < 8; ++j) v[j] = wp[j * 64];
            uint4 pkv = { pk2(v[0], v[1]), pk2(v[2], v[3]), pk2(v[4], v[5]), pk2(v[6], v[7]) };
            *(uint4*)(Bb + toff(col, c)) = pkv;
        }
    }
    __syncthreads();

    // --- MFMA: wave w = rows 32w..32w+31, all 64 cols ---
    const int l = tid & 63, w = tid >> 6;
    const int r0 = 32 * w + (l & 15);
    const int ci = l >> 4;
    f32x4 acc[2][4];
    #pragma unroll
    for (int a = 0; a < 2; ++a)
        #pragma unroll
        for (int bf = 0; bf < 4; ++bf) { acc[a][bf][0]=0.f; acc[a][bf][1]=0.f; acc[a][bf][2]=0.f; acc[a][bf][3]=0.f; }

    #pragma unroll
    for (int ks = 0; ks < 4; ++ks) {
        const int c = 4 * ks + ci;
        bf16x8 A0 = *(const bf16x8*)(Ab + toff(r0,      c));
        bf16x8 A1 = *(const bf16x8*)(Ab + toff(r0 + 16, c));
        #pragma unroll
        for (int bf = 0; bf < 4; ++bf) {
            bf16x8 Bf = *(const bf16x8*)(Bb + toff(16 * bf + (l & 15), c));
            acc[0][bf] = __builtin_amdgcn_mfma_f32_16x16x32_bf16(A0, Bf, acc[0][bf], 0, 0, 0);
            acc[1][bf] = __builtin_amdgcn_mfma_f32_16x16x32_bf16(A1, Bf, acc[1][bf], 0, 0, 0);
        }
    }

    // --- f1/f2 from f32 accumulators (exact): reduce over cols ---
    {
        float a1v[4], a2v[4];
        #pragma unroll
        for (int bf = 0; bf < 4; ++bf) {
            a1v[bf] = a1[ch * 64 + 16 * bf + (l & 15)];
            a2v[bf] = a2[ch * 64 + 16 * bf + (l & 15)];
        }
        #pragma unroll
        for (int a = 0; a < 2; ++a)
            #pragma unroll
            for (int reg = 0; reg < 4; ++reg) {
                float s1 = 0.f, s2 = 0.f;
                #pragma unroll
                for (int bf = 0; bf < 4; ++bf) {
                    s1 = fmaf(acc[a][bf][reg], a1v[bf], s1);
                    s2 = fmaf(acc[a][bf][reg], a2v[bf], s2);
                }
                #pragma unroll
                for (int m = 1; m < 16; m <<= 1) {
                    s1 += __shfl_xor(s1, m);
                    s2 += __shfl_xor(s2, m);
                }
                if ((l & 15) == 0) {
                    int r  = 16 * a + (l >> 4) * 4 + reg;
                    int ng = rt * 128 + 32 * w + r;
                    int bb = ng >> 10, n2 = ng & 1023;
                    f1p[(bb * NN + n2) * 4 + ch] = s1;
                    f2p[(bb * NN + n2) * 4 + ch] = s2;
                }
            }
    }
    __syncthreads();   // A region reused as C staging below

    // --- epilogue: C -> LDS (bf16) -> coalesced global ---
    unsigned short* cst = (unsigned short*)smem + w * 2048;   // 32 rows x 64 cols
    #pragma unroll
    for (int a = 0; a < 2; ++a)
        #pragma unroll
        for (int bf = 0; bf < 4; ++bf)
            #pragma unroll
            for (int reg = 0; reg < 4; ++reg) {
                int r   = 16 * a + (l >> 4) * 4 + reg;      // C/D: col=lane&15, row=(lane>>4)*4+reg
                int col = 16 * bf + (l & 15);
                cst[r * 64 + col] = bfbits(acc[a][bf][reg]);
            }
    WFENCE();
    const uint4* csv = (const uint4*)cst;                    // 256 uint4
    #pragma unroll
    for (int p = 0; p < 4; ++p) {
        int idx = p * 64 + l;
        uint4 v = csv[idx];
        int r = idx >> 3, o8 = idx & 7;
        int ng = rt * 128 + 32 * w + r;
        int bb = ng >> 10, n2 = ng & 1023;
        ((uint4*)hbu)[((size_t)(bb * NH + ch) * NN + n2) * 8 + o8] = v;
    }
}

// ---------------------------------------------------------------------------
// k_stats: per-(b,g,j) softmax-over-i stats. 2048 blocks (8 j x 32 i-chunks).
// Mub = per-head endpoint upper bound; D = sum_i exp(e2 - Mub); store Mub, 1/D.
// ---------------------------------------------------------------------------
__global__ __launch_bounds__(256) void k_stats(const float* __restrict__ f1p,
                                               const float* __restrict__ f2p,
                                               const float* __restrict__ P_l,
                                               float* __restrict__ Mp,
                                               float* __restrict__ Rp)
{
    __shared__ float4 f1s[1024];
    __shared__ float4 red[32][8];
    const int tid  = threadIdx.x;
    const int lane = tid & 63;
    const int b    = blockIdx.x >> 7;
    const int jt   = blockIdx.x & 127;
    const float4* f1p4 = (const float4*)f1p;
    const float4* f2p4 = (const float4*)f2p;

    #pragma unroll
    for (int q = 0; q < 4; ++q) f1s[tid + 256 * q] = f1p4[b * NN + tid + 256 * q];
    __syncthreads();

    // per-wave butterfly min/max over all 1024 entries
    float4 mn = make_float4( INFINITY,  INFINITY,  INFINITY,  INFINITY);
    float4 mx = make_float4(-INFINITY, -INFINITY, -INFINITY, -INFINITY);
    #pragma unroll
    for (int q = 0; q < 16; ++q) {
        float4 v = f1s[lane + 64 * q];
        mn = min4(mn, v);
        mx = max4(mx, v);
    }
    #pragma unroll
    for (int m = 32; m > 0; m >>= 1) {
        float4 on = make_float4(__shfl_xor(mn.x, m), __shfl_xor(mn.y, m), __shfl_xor(mn.z, m), __shfl_xor(mn.w, m));
        float4 ox = make_float4(__shfl_xor(mx.x, m), __shfl_xor(mx.y, m), __shfl_xor(mx.z, m), __shfl_xor(mx.w, m));
        mn = min4(mn, on);
        mx = max4(mx, ox);
    }

    float pl[4][4];
    #pragma unroll
    for (int hh = 0; hh < 4; ++hh)
        #pragma unroll
        for (int g = 0; g < 4; ++g) pl[hh][g] = P_l[hh * 4 + g];

    const int jj = tid & 7, ic = tid >> 3;
    const int j  = jt * 8 + jj;
    float4 f2v = f2p4[b * NN + j];
    float f2a[4] = {f2v.x, f2v.y, f2v.z, f2v.w};
    float mna[4] = {mn.x, mn.y, mn.z, mn.w};
    float mxa[4] = {mx.x, mx.y, mx.z, mx.w};
    float mub[4];
    #pragma unroll
    for (int g = 0; g < 4; ++g) {
        float s = 0.f;
        #pragma unroll
        for (int hh = 0; hh < 4; ++hh) {
            float base = (pl[hh][g] >= 0.f ? mxa[hh] : mna[hh]) + f2a[hh];
            s = fmaf(pl[hh][g], lrelu(base), s);
        }
        mub[g] = s;
    }

    float d[4] = {0.f, 0.f, 0.f, 0.f};
    #pragma unroll 4
    for (int ii = 0; ii < 32; ++ii) {
        int i = ic * 32 + ((ii + 2 * ic) & 31);    // bank rotation
        float4 f1v = f1s[i];
        float l0 = lrelu(f1v.x + f2a[0]);
        float l1 = lrelu(f1v.y + f2a[1]);
        float l2 = lrelu(f1v.z + f2a[2]);
        float l3 = lrelu(f1v.w + f2a[3]);
        #pragma unroll
        for (int g = 0; g < 4; ++g) {
            float e = fmaf(pl[0][g], l0, fmaf(pl[1][g], l1, fmaf(pl[2][g], l2, pl[3][g] * l3)));
            d[g] += __expf(e - mub[g]);
        }
    }
    red[ic][jj] = make_float4(d[0], d[1], d[2], d[3]);
    __syncthreads();
    if (tid < 8) {
        float4 t = red[0][tid];
        #pragma unroll
        for (int r = 1; r < 32; ++r) {
            float4 u = red[r][tid];
            t.x += u.x; t.y += u.y; t.z += u.z; t.w += u.w;
        }
        ((float4*)Rp)[b * NN + j] = make_float4(1.f / t.x, 1.f / t.y, 1.f / t.z, 1.f / t.w);
        ((float4*)Mp)[b * NN + j] = make_float4(mub[0], mub[1], mub[2], mub[3]);
    }
}

// ---------------------------------------------------------------------------
// k_agg: wave-per-row, XCD-swizzled so each XCD owns 2 batches (h L2-resident).
// Gather: uint4 loads (8 bf16), 2 edges/iter across lane halves, unroll-2.
// ---------------------------------------------------------------------------
__global__ __launch_bounds__(256) void k_agg(const float* __restrict__ adj,
                                             const float* __restrict__ x,
                                             const unsigned int* __restrict__ hb,
                                             const float* __restrict__ f1p,
                                             const float* __restrict__ f2p,
                                             const float* __restrict__ Mp,
                                             const float* __restrict__ Rp,
                                             const float* __restrict__ P_l,
                                             const float* __restrict__ P_w,
                                             float* __restrict__ out)
{
    __shared__ int   jl[4][CAP + 8];
    __shared__ float attlT[4][4][CAP + 8];   // [wave][head][edge]
    const int tid  = threadIdx.x;
    const int w    = tid >> 6;
    const int lane = tid & 63;
    const int orig = blockIdx.x;
    const int swz  = (orig & 7) * 512 + (orig >> 3);   // XCD-contiguous: 2 b's/XCD
    const int row  = swz * 4 + w;           // b*NN + i
    const int b    = row >> 10;

    // --- adj row load ---
    const float4* arow = (const float4*)adj + (size_t)row * 256;
    float4 av[4];
    #pragma unroll
    for (int q = 0; q < 4; ++q) av[q] = arow[lane + 64 * q];

    // --- in-wave ballot compaction ---
    const unsigned long long lt = (1ull << lane) - 1ull;
    int cnt = 0;
    #pragma unroll
    for (int q = 0; q < 4; ++q) {
        float vv[4] = {av[q].x, av[q].y, av[q].z, av[q].w};
        #pragma unroll
        for (int c = 0; c < 4; ++c) {
            bool nz = (vv[c] != 0.f);
            unsigned long long mask = __ballot(nz);
            if (nz) {
                int pos = cnt + __popcll(mask & lt);
                if (pos < CAP) jl[w][pos] = (lane + 64 * q) * 4 + c;
            }
            cnt += __popcll(mask);
        }
    }
    if (cnt > CAP) cnt = CAP;
    if (lane < 8) jl[w][cnt + lane] = 0;
    WFENCE();

    // --- att recompute (lane kk -> edge kk) ---
    float pl[4][4], pw[4][4];
    #pragma unroll
    for (int a_ = 0; a_ < 4; ++a_)
        #pragma unroll
        for (int g = 0; g < 4; ++g) {
            pl[a_][g] = P_l[a_ * 4 + g];
            pw[a_][g] = P_w[a_ * 4 + g];
        }
    const float4 f1v = ((const float4*)f1p)[row];
    for (int base = 0; base < cnt; base += 64) {
        int kk = base + lane;
        if (kk < cnt) {
            int j = jl[w][kk];
            float4 f2v = ((const float4*)f2p)[b * NN + j];
            float4 mv  = ((const float4*)Mp)[b * NN + j];
            float4 rv  = ((const float4*)Rp)[b * NN + j];
            float l0 = lrelu(f1v.x + f2v.x);
            float l1 = lrelu(f1v.y + f2v.y);
            float l2 = lrelu(f1v.z + f2v.z);
            float l3 = lrelu(f1v.w + f2v.w);
            float p0 = __expf(fmaf(pl[0][0], l0, fmaf(pl[1][0], l1, fmaf(pl[2][0], l2, pl[3][0] * l3))) - mv.x) * rv.x;
            float p1 = __expf(fmaf(pl[0][1], l0, fmaf(pl[1][1], l1, fmaf(pl[2][1], l2, pl[3][1] * l3))) - mv.y) * rv.y;
            float p2 = __expf(fmaf(pl[0][2], l0, fmaf(pl[1][2], l1, fmaf(pl[2][2], l2, pl[3][2] * l3))) - mv.z) * rv.z;
            float p3 = __expf(fmaf(pl[0][3], l0, fmaf(pl[1][3], l1, fmaf(pl[2][3], l2, pl[3][3] * l3))) - mv.w) * rv.w;
            #pragma unroll
            for (int g = 0; g < 4; ++g)
                attlT[w][g][kk] =
                    fmaf(p0, pw[0][g], fmaf(p1, pw[1][g], fmaf(p2, pw[2][g], p3 * pw[3][g])));
        }
    }
    if (lane < 8) {
        #pragma unroll
        for (int g = 0; g < 4; ++g) attlT[w][g][cnt + lane] = 0.f;
    }
    WFENCE();

    // --- gather: lane = (e2, hh, oct); uint4 = 8 bf16 per load, 2 edges/iter ---
    const int e2  = lane >> 5;
    const int sub = lane & 31;
    const int hh  = sub >> 3;
    const int oct = sub & 7;
    const uint4* hrow = (const uint4*)hb + ((size_t)(b * NH + hh) * NN) * 8 + oct;
    const float* atp = &attlT[w][hh][0];
    float acc[8];
    #pragma unroll
    for (int e = 0; e < 8; ++e) acc[e] = 0.f;

    #pragma unroll 2
    for (int base = 0; base < cnt; base += 8) {
        int j0 = jl[w][base     + e2];
        int j1 = jl[w][base + 2 + e2];
        int j2 = jl[w][base + 4 + e2];
        int j3 = jl[w][base + 6 + e2];
        uint4 u0 = hrow[(size_t)j0 * 8];
        uint4 u1 = hrow[(size_t)j1 * 8];
        uint4 u2 = hrow[(size_t)j2 * 8];
        uint4 u3 = hrow[(size_t)j3 * 8];
        float t0 = atp[base     + e2];
        float t1 = atp[base + 2 + e2];
        float t2 = atp[base + 4 + e2];
        float t3 = atp[base + 6 + e2];
        acc[0] = fmaf(t0, __uint_as_float(u0.x << 16),          acc[0]);
        acc[1] = fmaf(t0, __uint_as_float(u0.x & 0xffff0000u),  acc[1]);
        acc[2] = fmaf(t0, __uint_as_float(u0.y << 16),          acc[2]);
        acc[3] = fmaf(t0, __uint_as_float(u0.y & 0xffff0000u),  acc[3]);
        acc[4] = fmaf(t0, __uint_as_float(u0.z << 16),          acc[4]);
        acc[5] = fmaf(t0, __uint_as_float(u0.z & 0xffff0000u),  acc[5]);
        acc[6] = fmaf(t0, __uint_as_float(u0.w << 16),          acc[6]);
        acc[7] = fmaf(t0, __uint_as_float(u0.w & 0xffff0000u),  acc[7]);
        acc[0] = fmaf(t1, __uint_as_float(u1.x << 16),          acc[0]);
        acc[1] = fmaf(t1, __uint_as_float(u1.x & 0xffff0000u),  acc[1]);
        acc[2] = fmaf(t1, __uint_as_float(u1.y << 16),          acc[2]);
        acc[3] = fmaf(t1, __uint_as_float(u1.y & 0xffff0000u),  acc[3]);
        acc[4] = fmaf(t1, __uint_as_float(u1.z << 16),          acc[4]);
        acc[5] = fmaf(t1, __uint_as_float(u1.z & 0xffff0000u),  acc[5]);
        acc[6] = fmaf(t1, __uint_as_float(u1.w << 16),          acc[6]);
        acc[7] = fmaf(t1, __uint_as_float(u1.w & 0xffff0000u),  acc[7]);
        acc[0] = fmaf(t2, __uint_as_float(u2.x << 16),          acc[0]);
        acc[1] = fmaf(t2, __uint_as_float(u2.x & 0xffff0000u),  acc[1]);
        acc[2] = fmaf(t2, __uint_as_float(u2.y << 16),          acc[2]);
        acc[3] = fmaf(t2, __uint_as_float(u2.y & 0xffff0000u),  acc[3]);
        acc[4] = fmaf(t2, __uint_as_float(u2.z << 16),          acc[4]);
        acc[5] = fmaf(t2, __uint_as_float(u2.z & 0xffff0000u),  acc[5]);
        acc[6] = fmaf(t2, __uint_as_float(u2.w << 16),          acc[6]);
        acc[7] = fmaf(t2, __uint_as_float(u2.w & 0xffff0000u),  acc[7]);
        acc[0] = fmaf(t3, __uint_as_float(u3.x << 16),          acc[0]);
        acc[1] = fmaf(t3, __uint_as_float(u3.x & 0xffff0000u),  acc[1]);
        acc[2] = fmaf(t3, __uint_as_float(u3.y << 16),          acc[2]);
        acc[3] = fmaf(t3, __uint_as_float(u3.y & 0xffff0000u),  acc[3]);
        acc[4] = fmaf(t3, __uint_as_float(u3.z << 16),          acc[4]);
        acc[5] = fmaf(t3, __uint_as_float(u3.z & 0xffff0000u),  acc[5]);
        acc[6] = fmaf(t3, __uint_as_float(u3.w << 16),          acc[6]);
        acc[7] = fmaf(t3, __uint_as_float(u3.w & 0xffff0000u),  acc[7]);
    }

    // fold the two edge-halves together (both halves participate in shfl)
    #pragma unroll
    for (int e = 0; e < 8; ++e) acc[e] += __shfl_xor(acc[e], 32);

    if (e2 == 0) {
        const float4* x4 = (const float4*)x;
        float4 xa = x4[(size_t)row * 16 + oct * 2];
        float4 xb = x4[(size_t)row * 16 + oct * 2 + 1];
        float r0 = acc[0] + xa.x, r1 = acc[1] + xa.y, r2 = acc[2] + xa.z, r3 = acc[3] + xa.w;
        float r4 = acc[4] + xb.x, r5 = acc[5] + xb.y, r6 = acc[6] + xb.z, r7 = acc[7] + xb.w;
        float4 o4a, o4b;
        o4a.x = (r0 > 0.f) ? r0 : (__expf(r0) - 1.f);
        o4a.y = (r1 > 0.f) ? r1 : (__expf(r1) - 1.f);
        o4a.z = (r2 > 0.f) ? r2 : (__expf(r2) - 1.f);
        o4a.w = (r3 > 0.f) ? r3 : (__expf(r3) - 1.f);
        o4b.x = (r4 > 0.f) ? r4 : (__expf(r4) - 1.f);
        o4b.y = (r5 > 0.f) ? r5 : (__expf(r5) - 1.f);
        o4b.z = (r6 > 0.f) ? r6 : (__expf(r6) - 1.f);
        o4b.w = (r7 > 0.f) ? r7 : (__expf(r7) - 1.f);
        float4* op = (float4*)out + (size_t)row * 64 + hh * 16 + oct * 2;
        op[0] = o4a;
        op[1] = o4b;
    }
}

// ---------------------------------------------------------------------------
extern "C" void kernel_launch(void* const* d_in, const int* in_sizes, int n_in,
                              void* d_out, int out_size, void* d_ws, size_t ws_size,
                              hipStream_t stream)
{
    (void)in_sizes; (void)n_in; (void)out_size; (void)ws_size;
    const float* x   = (const float*)d_in[0];
    const float* adj = (const float*)d_in[1];
    const float* SE  = (const float*)d_in[2];
    const float* W   = (const float*)d_in[3];
    const float* a1  = (const float*)d_in[4];
    const float* a2  = (const float*)d_in[5];
    const float* P_l = (const float*)d_in[6];
    const float* P_w = (const float*)d_in[7];
    float* out = (float*)d_out;

    float* f1p = (float*)d_ws;                       // 65536 floats
    float* f2p = f1p + 65536;
    float* Mp  = f2p + 65536;
    float* Rp  = Mp  + 65536;
    unsigned int* hbu = (unsigned int*)(Rp + 65536); // 2M uints = 8 MB (bf16 h)

    k_proj <<<512,  256, 0, stream>>>(x, SE, W, a1, a2, hbu, f1p, f2p);
    k_stats<<<2048, 256, 0, stream>>>(f1p, f2p, P_l, Mp, Rp);
    k_agg  <<<4096, 256, 0, stream>>>(adj, x, hbu, f1p, f2p, Mp, Rp, P_l, P_w, out);
}